// Round 3
// baseline (592.859 us; speedup 1.0000x reference)
//
#include <hip/hip_runtime.h>

#define QN 512
#define TN 256
#define KPL 8              // columns per lane = QN / 64
#define RPL 4              // rows per lane    = TN / 64
#define INFV 1000000000.0f // matches jnp.float32(1e9)

// ---------------------------------------------------------------------------
// Cost matrix: C[b][q][t] = |out[b][q].x - tgt[b][t].x| + |out[b][q].y - tgt[b][t].y|
// ---------------------------------------------------------------------------
__global__ __launch_bounds__(256) void cost_kernel(const float2* __restrict__ outputs,
                                                   const float2* __restrict__ targets,
                                                   float* __restrict__ C) {
    const int t = threadIdx.x;
    const int q = blockIdx.x;
    const int b = blockIdx.y;
    float2 o = outputs[b * QN + q];
    float2 g = targets[b * TN + t];
    C[(size_t)(b * QN + q) * TN + t] = fabsf(o.x - g.x) + fabsf(o.y - g.y);
}

// lexicographic (value, index) min with DPP row_ror partner (16-lane rows)
template <int CTRL>
__device__ __forceinline__ void lexmin_dpp(float& bv, int& bj) {
    int ovi = __builtin_amdgcn_update_dpp(0, __builtin_bit_cast(int, bv), CTRL, 0xF, 0xF, true);
    int oji = __builtin_amdgcn_update_dpp(0, bj, CTRL, 0xF, 0xF, true);
    float ov = __builtin_bit_cast(float, ovi);
    if (ov < bv || (ov == bv && oji < bj)) { bv = ov; bj = oji; }
}

__device__ __forceinline__ float readlane_f(float v, int lane) {
    return __builtin_bit_cast(float, __builtin_amdgcn_readlane(__builtin_bit_cast(int, v), lane));
}

// compile-time-unrolled slot selects (no runtime-indexed arrays -> no scratch)
__device__ __forceinline__ float sel8f(const float a[KPL], int s) {
    float b0 = (s & 1) ? a[1] : a[0];
    float b1 = (s & 1) ? a[3] : a[2];
    float b2 = (s & 1) ? a[5] : a[4];
    float b3 = (s & 1) ? a[7] : a[6];
    float c0 = (s & 2) ? b1 : b0;
    float c1 = (s & 2) ? b3 : b2;
    return (s & 4) ? c1 : c0;
}
__device__ __forceinline__ int sel8i(const int a[KPL], int s) {
    int b0 = (s & 1) ? a[1] : a[0];
    int b1 = (s & 1) ? a[3] : a[2];
    int b2 = (s & 1) ? a[5] : a[4];
    int b3 = (s & 1) ? a[7] : a[6];
    int c0 = (s & 2) ? b1 : b0;
    int c1 = (s & 2) ? b3 : b2;
    return (s & 4) ? c1 : c0;
}
__device__ __forceinline__ float sel4f(const float a[RPL], int s) {
    float b0 = (s & 1) ? a[1] : a[0];
    float b1 = (s & 1) ? a[3] : a[2];
    return (s & 2) ? b1 : b0;
}
__device__ __forceinline__ unsigned long long sel8u64(const unsigned long long a[8], int s) {
    unsigned long long b0 = (s & 1) ? a[1] : a[0];
    unsigned long long b1 = (s & 1) ? a[3] : a[2];
    unsigned long long b2 = (s & 1) ? a[5] : a[4];
    unsigned long long b3 = (s & 1) ? a[7] : a[6];
    unsigned long long c0 = (s & 2) ? b1 : b0;
    unsigned long long c1 = (s & 2) ? b3 : b2;
    return (s & 4) ? c1 : c0;
}

// ---------------------------------------------------------------------------
// Jonker-Volgenant Hungarian, one wave per batch, zero LDS, register-resident.
// Per-column caches of the matched row's (u, tx, ty) remove the p-lookup and
// row-slot select from the per-iteration dependent chain. Bit-exact FP
// trajectory vs the JAX reference (same op order, fma == masked add/sub).
// ---------------------------------------------------------------------------
__global__ __launch_bounds__(64) void hung_kernel(const float2* __restrict__ outputs,
                                                  const float2* __restrict__ targets,
                                                  float* __restrict__ out_row,
                                                  float* __restrict__ out_col) {
    const int b = blockIdx.x;
    const int l = threadIdx.x;   // lane 0..63

    // row-distributed: row r = l + 64*s
    float tx_r[RPL], ty_r[RPL], u_r[RPL], rflag[RPL];
    #pragma unroll
    for (int s = 0; s < RPL; ++s) {
        float2 g = targets[b * TN + l + 64 * s];
        tx_r[s] = g.x; ty_r[s] = g.y; u_r[s] = 0.0f;
    }

    // column-distributed: col j = l + 64*k
    float ox[KPL], oy[KPL], v[KPL], minv[KPL];
    float uflag[KPL], uflagm1[KPL];          // used flags {0,1} / {−1,0}
    float upj[KPL], txp[KPL], typ[KPL];      // caches of u/tx/ty[p[j]]
    int way_r[KPL], p_r[KPL], jcol[KPL];
    #pragma unroll
    for (int k = 0; k < KPL; ++k) {
        float2 o = outputs[b * QN + l + 64 * k];
        ox[k] = o.x; oy[k] = o.y; v[k] = 0.0f;
        p_r[k] = -1; way_r[k] = QN; jcol[k] = l + 64 * k;
        upj[k] = 0.0f; txp[k] = 0.0f; typ[k] = 0.0f;
    }

    unsigned long long mm[8];                // matched-column bitmasks (uniform)
    #pragma unroll
    for (int s = 0; s < 8; ++s) mm[s] = 0ull;

    for (int i = 0; i < TN; ++i) {
        #pragma unroll
        for (int k = 0; k < KPL; ++k) { minv[k] = INFV; uflag[k] = 0.0f; uflagm1[k] = -1.0f; }
        #pragma unroll
        for (int s = 0; s < RPL; ++s) rflag[s] = 0.0f;

        // initial row = i: fetch row data, mark row used
        float ui0 = readlane_f(sel4f(u_r, i >> 6), i & 63);
        float txv = readlane_f(sel4f(tx_r, i >> 6), i & 63);
        float tyv = readlane_f(sel4f(ty_r, i >> 6), i & 63);
        #pragma unroll
        for (int s = 0; s < RPL; ++s) rflag[s] = (i == l + 64 * s) ? 1.0f : rflag[s];

        int j0s = QN;
        int jfree;
        for (;;) {
            // ---- scan: relax from row p[j0s] (data in ui0/txv/tyv) ----
            float masked[KPL];
            #pragma unroll
            for (int k = 0; k < KPL; ++k) {
                const float cost = fabsf(ox[k] - txv) + fabsf(oy[k] - tyv);
                const float cur  = (cost - ui0) - v[k];
                const float gate = fmaf(uflag[k], -INFV, minv[k]);   // used -> −huge
                const bool  better = cur < gate;
                minv[k]  = better ? cur : minv[k];
                way_r[k] = better ? j0s : way_r[k];
                masked[k] = fmaf(uflag[k], INFV, minv[k]);           // used -> ~1e9
            }

            // ---- per-lane lex tree (lower k wins ties => first-min) ----
            float a0v = (masked[1] < masked[0]) ? masked[1] : masked[0];
            int   a0j = (masked[1] < masked[0]) ? jcol[1] : jcol[0];
            float a1v = (masked[3] < masked[2]) ? masked[3] : masked[2];
            int   a1j = (masked[3] < masked[2]) ? jcol[3] : jcol[2];
            float a2v = (masked[5] < masked[4]) ? masked[5] : masked[4];
            int   a2j = (masked[5] < masked[4]) ? jcol[5] : jcol[4];
            float a3v = (masked[7] < masked[6]) ? masked[7] : masked[6];
            int   a3j = (masked[7] < masked[6]) ? jcol[7] : jcol[6];
            float b0v = (a1v < a0v) ? a1v : a0v;  int b0j = (a1v < a0v) ? a1j : a0j;
            float b1v = (a3v < a2v) ? a3v : a2v;  int b1j = (a3v < a2v) ? a3j : a2j;
            float bestv = (b1v < b0v) ? b1v : b0v; int bestj = (b1v < b0v) ? b1j : b0j;

            // ---- wave lex-min: 4 DPP row_ror + 4-row readlane combine ----
            lexmin_dpp<0x121>(bestv, bestj);
            lexmin_dpp<0x122>(bestv, bestj);
            lexmin_dpp<0x124>(bestv, bestj);
            lexmin_dpp<0x128>(bestv, bestj);
            float dv; int dj;
            {
                const float v0 = readlane_f(bestv, 0),  v1 = readlane_f(bestv, 16);
                const float v2 = readlane_f(bestv, 32), v3 = readlane_f(bestv, 48);
                const int   a0 = __builtin_amdgcn_readlane(bestj, 0);
                const int   a1 = __builtin_amdgcn_readlane(bestj, 16);
                const int   a2 = __builtin_amdgcn_readlane(bestj, 32);
                const int   a3 = __builtin_amdgcn_readlane(bestj, 48);
                dv = v0; dj = a0;
                if (v1 < dv || (v1 == dv && a1 < dj)) { dv = v1; dj = a1; }
                if (v2 < dv || (v2 == dv && a2 < dj)) { dv = v2; dj = a2; }
                if (v3 < dv || (v3 == dv && a3 < dj)) { dv = v3; dj = a3; }
            }
            const float delta = dv;
            const int   j1s   = __builtin_amdgcn_readfirstlane(dj);

            // ---- dual updates (fma == reference's masked add/sub, bit-exact) ----
            #pragma unroll
            for (int s = 0; s < RPL; ++s) u_r[s] = fmaf(rflag[s], delta, u_r[s]);
            #pragma unroll
            for (int k = 0; k < KPL; ++k) {
                v[k]    = fmaf(uflag[k],  -delta, v[k]);
                upj[k]  = fmaf(uflag[k],   delta, upj[k]);    // keep cache in sync
                minv[k] = fmaf(uflagm1[k], delta, minv[k]);   // unused -> minv - delta
            }

            // ---- termination: SALU matched-bit test (parallel with fetches) ----
            const int cslot = j1s >> 6, clane = j1s & 63;
            const bool isfree = (((sel8u64(mm, cslot) >> clane) & 1ull) == 0ull);
            if (isfree) { jfree = j1s; break; }

            // ---- next row's data straight from column caches (short chain) ----
            ui0 = readlane_f(sel8f(upj, cslot), clane);
            txv = readlane_f(sel8f(txp, cslot), clane);
            tyv = readlane_f(sel8f(typ, cslot), clane);

            // mark column j1 used
            #pragma unroll
            for (int k = 0; k < KPL; ++k) {
                const bool own = (j1s == jcol[k]);
                uflag[k]   = own ? 1.0f : uflag[k];
                uflagm1[k] = own ? 0.0f : uflagm1[k];
            }
            // mark row p[j1] used (off-chain: feeds next dual update only)
            const int i0s = __builtin_amdgcn_readlane(sel8i(p_r, cslot), clane);
            #pragma unroll
            for (int s = 0; s < RPL; ++s) rflag[s] = (i0s == l + 64 * s) ? 1.0f : rflag[s];

            j0s = j1s;
        }

        // ---- augment walk: p[jj] = p[way[jj]]; refresh caches from row data ----
        {
            int jj = jfree;
            for (;;) {
                const int jn = __builtin_amdgcn_readlane(sel8i(way_r, jj >> 6), jj & 63);
                int pn;
                if (jn == QN) pn = i;
                else pn = __builtin_amdgcn_readlane(sel8i(p_r, jn >> 6), jn & 63);
                const float uc = readlane_f(sel4f(u_r,  pn >> 6), pn & 63);
                const float tc = readlane_f(sel4f(tx_r, pn >> 6), pn & 63);
                const float yc = readlane_f(sel4f(ty_r, pn >> 6), pn & 63);
                #pragma unroll
                for (int k = 0; k < KPL; ++k) {
                    const bool own = (jj == jcol[k]);
                    p_r[k] = own ? pn : p_r[k];
                    upj[k] = own ? uc : upj[k];
                    txp[k] = own ? tc : txp[k];
                    typ[k] = own ? yc : typ[k];
                }
                if (jn == QN) break;
                jj = jn;
            }
            const int fslot = jfree >> 6;
            const unsigned long long fbit = 1ull << (jfree & 63);
            #pragma unroll
            for (int s = 0; s < 8; ++s) mm[s] = (fslot == s) ? (mm[s] | fbit) : mm[s];
        }
    }

    // ---- emit matched pairs sorted by query index ----
    int rank_base = 0;
    #pragma unroll
    for (int k = 0; k < KPL; ++k) {
        const int pq = p_r[k];
        const bool valid = pq >= 0;
        unsigned long long m = __ballot(valid);
        int below = __popcll(m & ((1ull << l) - 1ull));
        if (valid) {
            int r = rank_base + below;
            out_row[b * TN + r] = (float)jcol[k];
            out_col[b * TN + r] = (float)pq;
        }
        rank_base += __popcll(m);
    }
}

extern "C" void kernel_launch(void* const* d_in, const int* in_sizes, int n_in,
                              void* d_out, int out_size, void* d_ws, size_t ws_size,
                              hipStream_t stream) {
    const float2* outputs = (const float2*)d_in[0];   // [8,512,2] f32
    const float2* targets = (const float2*)d_in[1];   // [8,256,2] f32
    float* out = (float*)d_out;
    float* out_row = out;                 // [8,256] as float
    float* out_col = out + 8 * TN;        // [8,256] as float
    float* C       = out + 2 * 8 * TN;    // [8,512,256] f32

    dim3 gridC(QN, 8);
    cost_kernel<<<gridC, TN, 0, stream>>>(outputs, targets, C);
    hung_kernel<<<8, 64, 0, stream>>>(outputs, targets, out_row, out_col);
}

// Round 4
// 477.323 us; speedup vs baseline: 1.2421x; 1.2421x over previous
//
#include <hip/hip_runtime.h>

#define QN 512
#define TN 256
#define INFV 1000000000.0f // matches jnp.float32(1e9)

// ---------------------------------------------------------------------------
// Cost matrix: C[b][q][t] = |out[b][q].x - tgt[b][t].x| + |out[b][q].y - tgt[b][t].y|
// ---------------------------------------------------------------------------
__global__ __launch_bounds__(256) void cost_kernel(const float2* __restrict__ outputs,
                                                   const float2* __restrict__ targets,
                                                   float* __restrict__ C) {
    const int t = threadIdx.x;
    const int q = blockIdx.x;
    const int b = blockIdx.y;
    float2 o = outputs[b * QN + q];
    float2 g = targets[b * TN + t];
    C[(size_t)(b * QN + q) * TN + t] = fabsf(o.x - g.x) + fabsf(o.y - g.y);
}

__device__ __forceinline__ float readlane_f(float v, int lane) {
    return __builtin_bit_cast(float, __builtin_amdgcn_readlane(__builtin_bit_cast(int, v), lane));
}

template <int CTRL>
__device__ __forceinline__ float dppminf(float x) {
    int o = __builtin_amdgcn_update_dpp(0, __builtin_bit_cast(int, x), CTRL, 0xF, 0xF, true);
    return fminf(x, __builtin_bit_cast(float, o));
}
template <int CTRL>
__device__ __forceinline__ int dppmini(int x) {
    int o = __builtin_amdgcn_update_dpp(0, x, CTRL, 0xF, 0xF, true);
    return min(x, o);
}

// repetition + pure-register slot-select macros (NO arrays, NO allocas)
#define K8(X) X(0) X(1) X(2) X(3) X(4) X(5) X(6) X(7)
#define R4(X) X(0) X(1) X(2) X(3)
#define SEL8(n, s) ((s) & 4 ? ((s) & 2 ? ((s) & 1 ? n##7 : n##6) : ((s) & 1 ? n##5 : n##4)) \
                            : ((s) & 2 ? ((s) & 1 ? n##3 : n##2) : ((s) & 1 ? n##1 : n##0)))
#define SEL4(n, s) ((s) & 2 ? ((s) & 1 ? n##3 : n##2) : ((s) & 1 ? n##1 : n##0))

// ---------------------------------------------------------------------------
// Jonker-Volgenant Hungarian, one wave per batch, zero LDS, all-register.
// Bit-exact replica of the JAX reference's FP trajectory (same op order,
// fma == masked add/sub, first-min tie-break = smallest j among exact minima).
// ---------------------------------------------------------------------------
__global__ __launch_bounds__(64) void hung_kernel(const float2* __restrict__ outputs,
                                                  const float2* __restrict__ targets,
                                                  float* __restrict__ out_row,
                                                  float* __restrict__ out_col) {
    const int b = blockIdx.x;
    const int l = threadIdx.x;   // lane 0..63

    // row-distributed state: row r = l + 64*s
#define DECLR(s) float tx##s, ty##s, u##s, rf##s;
    R4(DECLR)
#define LOADR(s) { float2 g = targets[b * TN + l + 64 * s]; tx##s = g.x; ty##s = g.y; u##s = 0.0f; }
    R4(LOADR)

    // column-distributed state: col j = l + 64*k
#define DECLC(k) float ox##k, oy##k, v##k, minv##k, uf##k, ufm##k, up##k, txp##k, typ##k, mk##k; \
                 int way##k, p##k; const int jc##k = l + 64 * k;
    K8(DECLC)
#define LOADC(k) { float2 o = outputs[b * QN + l + 64 * k]; ox##k = o.x; oy##k = o.y; v##k = 0.0f; \
                   p##k = -1; way##k = QN; up##k = 0.0f; txp##k = 0.0f; typ##k = 0.0f; mk##k = 0.0f; }
    K8(LOADC)

    // matched-column bitmasks (wave-uniform -> SGPRs, SALU termination test)
#define DECLM(s) unsigned long long mm##s = 0ull;
    K8(DECLM)

    for (int i = 0; i < TN; ++i) {
#define INITC(k) minv##k = INFV; uf##k = 0.0f; ufm##k = -1.0f;
        K8(INITC)
#define INITR(s) rf##s = 0.0f;
        R4(INITR)

        // initial row = i: fetch row data, mark row used
        const int irs = i >> 6, irl = i & 63;
        float ui0 = readlane_f(SEL4(u,  irs), irl);
        float txv = readlane_f(SEL4(tx, irs), irl);
        float tyv = readlane_f(SEL4(ty, irs), irl);
#define MARKRI(s) rf##s = (i == l + 64 * s) ? 1.0f : rf##s;
        R4(MARKRI)

        int j0s = QN;
        int jfree;
        for (;;) {
            // ---- scan: relax from current row (data in ui0/txv/tyv) ----
#define SCAN(k) { const float cost = fabsf(ox##k - txv) + fabsf(oy##k - tyv); \
                  const float cur  = (cost - ui0) - v##k; \
                  const float gate = fmaf(uf##k, -INFV, minv##k); \
                  const bool better = cur < gate; \
                  minv##k = better ? cur : minv##k; \
                  way##k  = better ? j0s : way##k; \
                  mk##k   = fmaf(uf##k, INFV, minv##k); }
            K8(SCAN)

            // ---- phase 1: wave-wide exact min value == delta ----
            float t0 = fminf(mk0, mk1), t1 = fminf(mk2, mk3);
            float t2 = fminf(mk4, mk5), t3 = fminf(mk6, mk7);
            float lmin = fminf(fminf(t0, t1), fminf(t2, t3));
            lmin = dppminf<0x121>(lmin);   // row_ror:1
            lmin = dppminf<0x122>(lmin);   // row_ror:2
            lmin = dppminf<0x124>(lmin);   // row_ror:4
            lmin = dppminf<0x128>(lmin);   // row_ror:8
            const float delta = fminf(fminf(readlane_f(lmin, 0),  readlane_f(lmin, 16)),
                                      fminf(readlane_f(lmin, 32), readlane_f(lmin, 48)));

            // ---- phase 2: smallest j with mk == delta (first-min tie-break) ----
            unsigned em = 0u;
#define EQM(k) em |= (mk##k == delta) ? (1u << k) : 0u;
            K8(EQM)
            int cj = em ? (int)((unsigned)((__ffs(em) - 1) << 6) | (unsigned)l) : 1024;
            cj = dppmini<0x121>(cj);
            cj = dppmini<0x122>(cj);
            cj = dppmini<0x124>(cj);
            cj = dppmini<0x128>(cj);
            const int j1s = min(min(__builtin_amdgcn_readlane(cj, 0),  __builtin_amdgcn_readlane(cj, 16)),
                                min(__builtin_amdgcn_readlane(cj, 32), __builtin_amdgcn_readlane(cj, 48)));

            // ---- dual updates (fma == reference's masked add/sub, bit-exact) ----
#define UPDR(s) u##s = fmaf(rf##s, delta, u##s);
            R4(UPDR)
#define UPDC(k) { v##k  = fmaf(uf##k,  -delta, v##k); \
                  up##k = fmaf(uf##k,   delta, up##k); \
                  minv##k = fmaf(ufm##k, delta, minv##k); }
            K8(UPDC)

            // ---- termination: SALU matched-bit test ----
            const int cslot = j1s >> 6, clane = j1s & 63;
            const bool isfree = (((SEL8(mm, cslot) >> clane) & 1ull) == 0ull);
            if (isfree) { jfree = j1s; break; }

            // ---- next row's data straight from the picked column's caches ----
            ui0 = readlane_f(SEL8(up,  cslot), clane);
            txv = readlane_f(SEL8(txp, cslot), clane);
            tyv = readlane_f(SEL8(typ, cslot), clane);

            // mark column j1 used
#define MARKC(k) { const bool own = (j1s == jc##k); \
                   uf##k  = own ? 1.0f : uf##k; \
                   ufm##k = own ? 0.0f : ufm##k; }
            K8(MARKC)
            // mark row p[j1] used (off-chain: feeds next dual update only)
            const int i0s = __builtin_amdgcn_readlane(SEL8(p, cslot), clane);
#define MARKR(s) rf##s = (i0s == l + 64 * s) ? 1.0f : rf##s;
            R4(MARKR)

            j0s = j1s;
        }

        // ---- augment walk: p[jj] = p[way[jj]]; refresh caches from row data ----
        {
            int jj = jfree;
            for (;;) {
                const int jn = __builtin_amdgcn_readlane(SEL8(way, jj >> 6), jj & 63);
                int pn;
                if (jn == QN) pn = i;
                else pn = __builtin_amdgcn_readlane(SEL8(p, jn >> 6), jn & 63);
                const float uc = readlane_f(SEL4(u,  pn >> 6), pn & 63);
                const float tc = readlane_f(SEL4(tx, pn >> 6), pn & 63);
                const float yc = readlane_f(SEL4(ty, pn >> 6), pn & 63);
#define SETP(k) { const bool own = (jj == jc##k); \
                  p##k   = own ? pn : p##k; \
                  up##k  = own ? uc : up##k; \
                  txp##k = own ? tc : txp##k; \
                  typ##k = own ? yc : typ##k; }
                K8(SETP)
                if (jn == QN) break;
                jj = jn;
            }
            const int fs = jfree >> 6;
            const unsigned long long fb = 1ull << (jfree & 63);
#define SETM(s) mm##s = (fs == s) ? (mm##s | fb) : mm##s;
            K8(SETM)
        }
    }

    // ---- emit matched pairs sorted by query index ----
    int rank_base = 0;
#define EMIT(k) { const int pq = p##k; const bool valid = pq >= 0; \
                  unsigned long long m = __ballot(valid); \
                  int below = __popcll(m & ((1ull << l) - 1ull)); \
                  if (valid) { int r = rank_base + below; \
                               out_row[b * TN + r] = (float)jc##k; \
                               out_col[b * TN + r] = (float)pq; } \
                  rank_base += __popcll(m); }
    K8(EMIT)
}

extern "C" void kernel_launch(void* const* d_in, const int* in_sizes, int n_in,
                              void* d_out, int out_size, void* d_ws, size_t ws_size,
                              hipStream_t stream) {
    const float2* outputs = (const float2*)d_in[0];   // [8,512,2] f32
    const float2* targets = (const float2*)d_in[1];   // [8,256,2] f32
    float* out = (float*)d_out;
    float* out_row = out;                 // [8,256] as float
    float* out_col = out + 8 * TN;        // [8,256] as float
    float* C       = out + 2 * 8 * TN;    // [8,512,256] f32

    dim3 gridC(QN, 8);
    cost_kernel<<<gridC, TN, 0, stream>>>(outputs, targets, C);
    hung_kernel<<<8, 64, 0, stream>>>(outputs, targets, out_row, out_col);
}

// Round 5
// 475.063 us; speedup vs baseline: 1.2480x; 1.0048x over previous
//
#include <hip/hip_runtime.h>

#define QN 512
#define TN 256
#define INFV 1000000000.0f // matches jnp.float32(1e9)

// ---------------------------------------------------------------------------
// Cost matrix: C[b][q][t] = |out[b][q].x - tgt[b][t].x| + |out[b][q].y - tgt[b][t].y|
// ---------------------------------------------------------------------------
__global__ __launch_bounds__(256) void cost_kernel(const float2* __restrict__ outputs,
                                                   const float2* __restrict__ targets,
                                                   float* __restrict__ C) {
    const int t = threadIdx.x;
    const int q = blockIdx.x;
    const int b = blockIdx.y;
    float2 o = outputs[b * QN + q];
    float2 g = targets[b * TN + t];
    C[(size_t)(b * QN + q) * TN + t] = fabsf(o.x - g.x) + fabsf(o.y - g.y);
}

__device__ __forceinline__ float readlane_f(float v, int lane) {
    return __builtin_bit_cast(float, __builtin_amdgcn_readlane(__builtin_bit_cast(int, v), lane));
}

__device__ __forceinline__ unsigned long long umin2(unsigned long long a, unsigned long long b) {
    return a < b ? a : b;   // v_cmp_lt_u64 + 2 cndmask
}

// DPP-shifted copy of a u64 (two independent 32-bit DPP movs)
template <int CTRL>
__device__ __forceinline__ unsigned long long dpp_u64(unsigned long long x) {
    int2 s = __builtin_bit_cast(int2, x);
    int2 t;
    t.x = __builtin_amdgcn_update_dpp(0, s.x, CTRL, 0xF, 0xF, true);
    t.y = __builtin_amdgcn_update_dpp(0, s.y, CTRL, 0xF, 0xF, true);
    return __builtin_bit_cast(unsigned long long, t);
}

// repetition + pure-register slot-select macros (NO arrays, NO allocas)
#define K8(X) X(0) X(1) X(2) X(3) X(4) X(5) X(6) X(7)
#define R4(X) X(0) X(1) X(2) X(3)
#define SEL8(n, s) ((s) & 4 ? ((s) & 2 ? ((s) & 1 ? n##7 : n##6) : ((s) & 1 ? n##5 : n##4)) \
                            : ((s) & 2 ? ((s) & 1 ? n##3 : n##2) : ((s) & 1 ? n##1 : n##0)))
#define SEL4(n, s) ((s) & 2 ? ((s) & 1 ? n##3 : n##2) : ((s) & 1 ? n##1 : n##0))

// ---------------------------------------------------------------------------
// Jonker-Volgenant Hungarian, one wave per batch, zero LDS, all-register.
// Single-pass packed-u64 lexicographic wave reduce (9 two-way levels total)
// delivers (delta, j1) together. Bit-exact FP trajectory vs the JAX reference.
// ---------------------------------------------------------------------------
__global__ __launch_bounds__(64, 1) void hung_kernel(const float2* __restrict__ outputs,
                                                     const float2* __restrict__ targets,
                                                     float* __restrict__ out_row,
                                                     float* __restrict__ out_col) {
    const int b = blockIdx.x;
    const int l = threadIdx.x;   // lane 0..63

    // row-distributed state: row r = l + 64*s
#define DECLR(s) float tx##s, ty##s, u##s, rf##s;
    R4(DECLR)
#define LOADR(s) { float2 g = targets[b * TN + l + 64 * s]; tx##s = g.x; ty##s = g.y; u##s = 0.0f; }
    R4(LOADR)

    // column-distributed state: col j = l + 64*k
#define DECLC(k) float ox##k, oy##k, v##k, minv##k, uf##k, ufm##k, up##k, txp##k, typ##k; \
                 int way##k, p##k; const int jc##k = l + 64 * k;
    K8(DECLC)
#define LOADC(k) { float2 o = outputs[b * QN + l + 64 * k]; ox##k = o.x; oy##k = o.y; v##k = 0.0f; \
                   p##k = -1; way##k = QN; up##k = 0.0f; txp##k = 0.0f; typ##k = 0.0f; }
    K8(LOADC)

    // matched-column bitmasks (wave-uniform -> SGPRs, SALU termination test)
#define DECLM(s) unsigned long long mm##s = 0ull;
    K8(DECLM)

    for (int i = 0; i < TN; ++i) {
#define INITC(k) minv##k = INFV; uf##k = 0.0f; ufm##k = -1.0f;
        K8(INITC)
#define INITR(s) rf##s = 0.0f;
        R4(INITR)

        // initial row = i: fetch row data, mark row used
        const int irs = i >> 6, irl = i & 63;
        float ui0 = readlane_f(SEL4(u,  irs), irl);
        float txv = readlane_f(SEL4(tx, irs), irl);
        float tyv = readlane_f(SEL4(ty, irs), irl);
#define MARKRI(s) rf##s = (i == l + 64 * s) ? 1.0f : rf##s;
        R4(MARKRI)

        int j0s = QN;
        int jfree;
        for (;;) {
            // ---- scan + pack: relax, build 64-bit lex keys {tv(mk) : j} ----
#define DECLPK(k) unsigned long long pk##k;
            K8(DECLPK)
#define SCAN(k) { const float cost = fabsf(ox##k - txv) + fabsf(oy##k - tyv); \
                  const float cur  = (cost - ui0) - v##k; \
                  const float gate = fmaf(uf##k, -INFV, minv##k); \
                  const bool better = cur < gate; \
                  minv##k = better ? cur : minv##k; \
                  way##k  = better ? j0s : way##k; \
                  const float mk = fmaf(uf##k, INFV, minv##k); \
                  const int bi = __builtin_bit_cast(int, mk); \
                  const int tv = bi ^ ((bi >> 31) | (int)0x80000000); \
                  int2 pr; pr.x = jc##k; pr.y = tv; \
                  pk##k = __builtin_bit_cast(unsigned long long, pr); }
            K8(SCAN)

            // ---- per-lane depth-3 tree (u64 lex: value asc, then j asc) ----
            unsigned long long q0 = umin2(pk0, pk1), q1 = umin2(pk2, pk3);
            unsigned long long q2 = umin2(pk4, pk5), q3 = umin2(pk6, pk7);
            unsigned long long best = umin2(umin2(q0, q1), umin2(q2, q3));

            // ---- 6-level wave reduce: row_ror 1,2,4,8 + row_bcast15/31 ----
            best = umin2(best, dpp_u64<0x121>(best));
            best = umin2(best, dpp_u64<0x122>(best));
            best = umin2(best, dpp_u64<0x124>(best));
            best = umin2(best, dpp_u64<0x128>(best));
            best = umin2(best, dpp_u64<0x142>(best));   // row_bcast:15
            best = umin2(best, dpp_u64<0x143>(best));   // row_bcast:31

            // ---- extract (delta, j1) as wave-uniform scalars ----
            const int2 bs = __builtin_bit_cast(int2, best);
            const int j1s  = __builtin_amdgcn_readlane(bs.x, 63);
            const int s_tv = __builtin_amdgcn_readlane(bs.y, 63);
            const int um = (~s_tv >> 31) | (int)0x80000000;   // inverse transform
            const float delta = __builtin_bit_cast(float, s_tv ^ um);

            // ---- dual updates (fma == reference's masked add/sub, bit-exact) ----
#define UPDR(s) u##s = fmaf(rf##s, delta, u##s);
            R4(UPDR)
#define UPDC(k) { v##k    = fmaf(uf##k,  -delta, v##k); \
                  up##k   = fmaf(uf##k,   delta, up##k); \
                  minv##k = fmaf(ufm##k,  delta, minv##k); }
            K8(UPDC)

            // ---- termination: SALU matched-bit test ----
            const int cslot = j1s >> 6, clane = j1s & 63;
            const bool isfree = (((SEL8(mm, cslot) >> clane) & 1ull) == 0ull);
            if (isfree) { jfree = j1s; break; }

            // ---- next row's data straight from the picked column's caches ----
            ui0 = readlane_f(SEL8(up,  cslot), clane);
            txv = readlane_f(SEL8(txp, cslot), clane);
            tyv = readlane_f(SEL8(typ, cslot), clane);

            // mark column j1 used
#define MARKC(k) { const bool own = (j1s == jc##k); \
                   uf##k  = own ? 1.0f : uf##k; \
                   ufm##k = own ? 0.0f : ufm##k; }
            K8(MARKC)
            // mark row p[j1] used (off-chain: feeds next dual update only)
            const int i0s = __builtin_amdgcn_readlane(SEL8(p, cslot), clane);
#define MARKR(s) rf##s = (i0s == l + 64 * s) ? 1.0f : rf##s;
            R4(MARKR)

            j0s = j1s;
        }

        // ---- augment walk: p[jj] = p[way[jj]]; refresh caches from row data ----
        {
            int jj = jfree;
            for (;;) {
                const int jn = __builtin_amdgcn_readlane(SEL8(way, jj >> 6), jj & 63);
                int pn;
                if (jn == QN) pn = i;
                else pn = __builtin_amdgcn_readlane(SEL8(p, jn >> 6), jn & 63);
                const float uc = readlane_f(SEL4(u,  pn >> 6), pn & 63);
                const float tc = readlane_f(SEL4(tx, pn >> 6), pn & 63);
                const float yc = readlane_f(SEL4(ty, pn >> 6), pn & 63);
#define SETP(k) { const bool own = (jj == jc##k); \
                  p##k   = own ? pn : p##k; \
                  up##k  = own ? uc : up##k; \
                  txp##k = own ? tc : txp##k; \
                  typ##k = own ? yc : typ##k; }
                K8(SETP)
                if (jn == QN) break;
                jj = jn;
            }
            const int fs = jfree >> 6;
            const unsigned long long fb = 1ull << (jfree & 63);
#define SETM(s) mm##s = (fs == s) ? (mm##s | fb) : mm##s;
            K8(SETM)
        }
    }

    // ---- emit matched pairs sorted by query index ----
    int rank_base = 0;
#define EMIT(k) { const int pq = p##k; const bool valid = pq >= 0; \
                  unsigned long long m = __ballot(valid); \
                  int below = __popcll(m & ((1ull << l) - 1ull)); \
                  if (valid) { int r = rank_base + below; \
                               out_row[b * TN + r] = (float)jc##k; \
                               out_col[b * TN + r] = (float)pq; } \
                  rank_base += __popcll(m); }
    K8(EMIT)
}

extern "C" void kernel_launch(void* const* d_in, const int* in_sizes, int n_in,
                              void* d_out, int out_size, void* d_ws, size_t ws_size,
                              hipStream_t stream) {
    const float2* outputs = (const float2*)d_in[0];   // [8,512,2] f32
    const float2* targets = (const float2*)d_in[1];   // [8,256,2] f32
    float* out = (float*)d_out;
    float* out_row = out;                 // [8,256] as float
    float* out_col = out + 8 * TN;        // [8,256] as float
    float* C       = out + 2 * 8 * TN;    // [8,512,256] f32

    dim3 gridC(QN, 8);
    cost_kernel<<<gridC, TN, 0, stream>>>(outputs, targets, C);
    hung_kernel<<<8, 64, 0, stream>>>(outputs, targets, out_row, out_col);
}